// Round 2
// 1235.934 us; speedup vs baseline: 1.2117x; 1.2117x over previous
//
#include <hip/hip_runtime.h>
#include <stdint.h>

typedef unsigned int u32;

#define S_DIM 2048
#define R_DIM 384
#define C_DIM 64

// float-offsets into d_ws (~3.74 MB used)
#define OFF_MASKT 0          // [384][2048] mask transposed, fp32
#define OFF_QRED  786432     // [384][4][64] per-wave qsum partials (k1-internal)
#define OFF_MSUM  884736     // [384][4]
#define OFF_QH    886272     // [384][64] scaled query
#define OFF_O     910848     // [384][64] per-column attention output o
// end: 935424 floats
// qred region is dead after k1 -> reuse it for fused-LN gate weights:
#define OFF_WG2   786432     // [64][64]  lnw[c]*wg[c][j]
#define OFF_CG    790528     // [64]      sum_c wg2[c][j]
#define OFF_DG    790592     // [64]      sum_c lnb[c]*wg[c][j] + bg[j]

__device__ __forceinline__ float bflo(u32 u){ return __uint_as_float(u << 16); }
__device__ __forceinline__ float bfhi(u32 u){ return __uint_as_float(u & 0xffff0000u); }
__device__ __forceinline__ u32 packbf2(float a, float b){
    u32 xa = __float_as_uint(a), xb = __float_as_uint(b);
    u32 ra = (xa + 0x7fffu + ((xa >> 16) & 1u)) >> 16;   // RNE
    u32 rb = (xb + 0x7fffu + ((xb >> 16) & 1u)) >> 16;
    return (ra & 0xffffu) | (rb << 16);
}
__device__ __forceinline__ void u4tof8(uint4 u, float* f){
    f[0]=bflo(u.x); f[1]=bfhi(u.x); f[2]=bflo(u.y); f[3]=bfhi(u.y);
    f[4]=bflo(u.z); f[5]=bfhi(u.z); f[6]=bflo(u.w); f[7]=bfhi(u.w);
}

// ---------------- prep: mask [S][R] fp32 -> [R][S] fp32 ----------------------------
__global__ void prep_mask(const float* __restrict__ mask, float* __restrict__ maskT)
{
    const int tid = blockIdx.x * 256 + threadIdx.x;   // over S*R, coalesced read
    const int s = tid / R_DIM;
    const int r = tid - s * R_DIM;
    maskT[(size_t)r * S_DIM + s] = mask[tid];
}

// ---------------- prep: fold LayerNorm into gate matmul ----------------------------
// wg2[c][j] = lnw[c]*wg[c][j]; cg[j] = sum_c wg2[c][j]; dg[j] = sum_c lnb[c]*wg[c][j] + bg[j]
__global__ void prep_w(const float* __restrict__ lnw, const float* __restrict__ lnb,
                       const float* __restrict__ wg,  const float* __restrict__ bg,
                       float* __restrict__ wg2, float* __restrict__ cg,
                       float* __restrict__ dg)
{
    const int j = threadIdx.x;   // 64
    float c_acc = 0.f, d_acc = 0.f;
    for (int c = 0; c < 64; ++c){
        float w  = wg[c*64 + j];
        float w2 = lnw[c] * w;
        wg2[c*64 + j] = w2;
        c_acc += w2;
        d_acc = fmaf(lnb[c], w, d_acc);
    }
    cg[j] = c_acc;
    dg[j] = d_acc + bg[j];
}

// ---------------- K1: per-column LN + k/v + pooled q + softmax + o ------------------
// one block per r; kv kept in LDS (bf16-packed), cross-wave scalars via global scratch
__global__ __launch_bounds__(256, 2) void k1_kv_softmax(
    const float* __restrict__ m,
    const float* __restrict__ lnw, const float* __restrict__ lnb,
    const float* __restrict__ wq,  const float* __restrict__ wk,
    const float* __restrict__ wv,
    const float* __restrict__ maskT,
    float* __restrict__ qred,
    float* __restrict__ msum,
    float* __restrict__ qh,
    float* __restrict__ otab)
{
    __shared__ uint4 kv[S_DIM * 2];   // exactly 64 KB: [s][0]=k bf16x8, [s][1]=v bf16x8

    const int t    = threadIdx.x;
    const int r    = blockIdx.x;
    const int w    = t >> 6;
    const int lane = t & 63;

    float qacc[64];
    #pragma unroll
    for (int c = 0; c < 64; ++c) qacc[c] = 0.f;
    float macc = 0.f;

    for (int it = 0; it < 8; ++it){
        const int s = it * 256 + t;
        const float4* mrow = reinterpret_cast<const float4*>(m + ((size_t)s * R_DIM + r) * C_DIM);
        float xn[64];
        #pragma unroll
        for (int q4 = 0; q4 < 16; ++q4){
            float4 f = mrow[q4];
            xn[q4*4+0]=f.x; xn[q4*4+1]=f.y; xn[q4*4+2]=f.z; xn[q4*4+3]=f.w;
        }

        float sm = 0.f, sq = 0.f;
        #pragma unroll
        for (int c = 0; c < 64; ++c){ sm += xn[c]; sq = fmaf(xn[c], xn[c], sq); }
        float mu  = sm * (1.f/64.f);
        float var = fmaf(-mu, mu, sq * (1.f/64.f));
        float rs  = rsqrtf(var + 1e-5f);
        #pragma unroll
        for (int c = 0; c < 64; ++c)
            xn[c] = fmaf((xn[c]-mu)*rs, lnw[c], lnb[c]);

        float mk = maskT[(size_t)r * S_DIM + s];
        macc += mk;
        #pragma unroll
        for (int c = 0; c < 64; ++c) qacc[c] = fmaf(xn[c], mk, qacc[c]);

        float kk[8], vv[8];
        #pragma unroll
        for (int ch = 0; ch < 8; ++ch){ kk[ch]=0.f; vv[ch]=0.f; }
        #pragma unroll
        for (int c = 0; c < 64; ++c){
            float xc = xn[c];
            #pragma unroll
            for (int ch = 0; ch < 8; ++ch){
                kk[ch] = fmaf(xc, wk[c*8 + ch], kk[ch]);
                vv[ch] = fmaf(xc, wv[c*8 + ch], vv[ch]);
            }
        }
        kv[s*2  ] = make_uint4(packbf2(kk[0],kk[1]),packbf2(kk[2],kk[3]),
                               packbf2(kk[4],kk[5]),packbf2(kk[6],kk[7]));
        kv[s*2+1] = make_uint4(packbf2(vv[0],vv[1]),packbf2(vv[2],vv[3]),
                               packbf2(vv[4],vv[5]),packbf2(vv[6],vv[7]));
    }

    // elementwise butterfly reduce qacc over the 64 lanes; lane c keeps channel c
    float myq = 0.f;
    #pragma unroll
    for (int c = 0; c < 64; ++c){
        float v = qacc[c];
        v += __shfl_xor(v, 1);  v += __shfl_xor(v, 2);  v += __shfl_xor(v, 4);
        v += __shfl_xor(v, 8);  v += __shfl_xor(v, 16); v += __shfl_xor(v, 32);
        myq = (lane == c) ? v : myq;
    }
    qred[r*256 + w*64 + lane] = myq;
    {
        float v = macc;
        v += __shfl_xor(v, 1);  v += __shfl_xor(v, 2);  v += __shfl_xor(v, 4);
        v += __shfl_xor(v, 8);  v += __shfl_xor(v, 16); v += __shfl_xor(v, 32);
        if (lane == 0) msum[r*4 + w] = v;
    }
    __threadfence_block();
    __syncthreads();

    // q = (masked-mean(xn) @ wq) * 8^-0.5     (volatile reads: bypass stale L1)
    volatile const float* vqred = qred;
    volatile const float* vmsum = msum;
    if (t < 64){
        float ms   = vmsum[r*4+0] + vmsum[r*4+1] + vmsum[r*4+2] + vmsum[r*4+3];
        float invD = 1.f / (ms + 1e-10f);
        float acc  = 0.f;
        for (int c = 0; c < 64; ++c){
            float qm = (vqred[r*256 + c] + vqred[r*256 + 64 + c] +
                        vqred[r*256 + 128 + c] + vqred[r*256 + 192 + c]) * invD;
            acc = fmaf(qm, wq[c*64 + t], acc);
        }
        qh[r*64 + t] = acc * 0.35355339059327373f;
    }
    __threadfence_block();
    __syncthreads();

    // per-head online softmax over s; 32 lanes per head
    volatile const float* vqh = qh;
    const int h   = t >> 5;
    const int sub = t & 31;
    float qv[8];
    #pragma unroll
    for (int j = 0; j < 8; ++j) qv[j] = vqh[r*64 + h*8 + j];

    float mx = -1e30f, ls = 0.f, oa[8];
    #pragma unroll
    for (int j = 0; j < 8; ++j) oa[j] = 0.f;

    for (int j2 = 0; j2 < 64; ++j2){
        const int s = j2*32 + sub;
        float kf[8]; u4tof8(kv[s*2], kf);
        float mk = maskT[(size_t)r * S_DIM + s];
        float logit = 1e9f * (mk - 1.f);
        #pragma unroll
        for (int j = 0; j < 8; ++j) logit = fmaf(qv[j], kf[j], logit);
        float nm = fmaxf(mx, logit);
        float p  = __expf(logit - nm);
        float cr = __expf(mx - nm);
        float vf[8]; u4tof8(kv[s*2+1], vf);
        ls = fmaf(ls, cr, p);
        #pragma unroll
        for (int j = 0; j < 8; ++j) oa[j] = fmaf(oa[j], cr, p * vf[j]);
        mx = nm;
    }
    #pragma unroll
    for (int xm = 16; xm >= 1; xm >>= 1){
        float m2 = __shfl_xor(mx, xm);
        float l2 = __shfl_xor(ls, xm);
        float nm = fmaxf(mx, m2);
        float c1 = __expf(mx - nm);
        float c2 = __expf(m2 - nm);
        ls = ls*c1 + l2*c2;
        #pragma unroll
        for (int j = 0; j < 8; ++j){
            float o2 = __shfl_xor(oa[j], xm);
            oa[j] = oa[j]*c1 + o2*c2;
        }
        mx = nm;
    }
    if (sub == 0){
        float inv = 1.f / ls;
        #pragma unroll
        for (int j = 0; j < 8; ++j) otab[r*64 + h*8 + j] = oa[j] * inv;
    }
}

// ---------------- K2: fused-LN gate + output projection (spill-free) ----------------
// one thread per (s,r) element; LN folded into the gate matmul so xn[64] is never
// materialized. Peak live set: raw[64] (reused as gated[64]) + acc[8] + addressing.
__global__ __launch_bounds__(256, 2) void k2_gate_out(
    const float* __restrict__ m,
    const float* __restrict__ wg2, const float* __restrict__ cg,
    const float* __restrict__ dg,
    const float* __restrict__ wo,  const float* __restrict__ bo,
    const float* __restrict__ otab,
    float* __restrict__ out)
{
    const int tid = blockIdx.x * 256 + threadIdx.x;   // tid = s*384 + r
    const int r   = tid % R_DIM;

    const float4* xrow = reinterpret_cast<const float4*>(m + (size_t)tid * C_DIM);

    // pass 1: stream x, accumulate LN stats + raw gate logits (x consumed immediately)
    float raw[64];
    #pragma unroll
    for (int j = 0; j < 64; ++j) raw[j] = 0.f;
    float sm = 0.f, sq = 0.f;

    #pragma unroll
    for (int c4 = 0; c4 < 16; ++c4){
        float4 f = xrow[c4];
        float xs[4] = {f.x, f.y, f.z, f.w};
        #pragma unroll
        for (int cc = 0; cc < 4; ++cc){
            const int c = c4*4 + cc;
            const float x = xs[cc];
            sm += x;
            sq = fmaf(x, x, sq);
            #pragma unroll
            for (int j = 0; j < 64; ++j)
                raw[j] = fmaf(x, wg2[c*64 + j], raw[j]);
        }
    }

    const float mu = sm * (1.f/64.f);
    const float rs = rsqrtf(fmaf(-mu, mu, sq * (1.f/64.f)) + 1e-5f);

    // gate: logit[j] = rs*(raw[j] - mu*cg[j]) + dg[j];  gated[j] = o[j]*sigmoid(logit)
    const float4* o4 = reinterpret_cast<const float4*>(otab + (size_t)r * 64);
    #pragma unroll
    for (int j4 = 0; j4 < 16; ++j4){
        float4 ov = o4[j4];
        float os[4] = {ov.x, ov.y, ov.z, ov.w};
        #pragma unroll
        for (int jj = 0; jj < 4; ++jj){
            const int j = j4*4 + jj;
            float lg = fmaf(rs, fmaf(-mu, cg[j], raw[j]), dg[j]);
            raw[j] = os[jj] / (1.f + __expf(-lg));   // raw[] becomes gated[]
        }
    }

    // out = gated @ wo + bo
    float4* orow = reinterpret_cast<float4*>(out + (size_t)tid * C_DIM);
    #pragma unroll
    for (int cb = 0; cb < 8; ++cb){
        float acc[8];
        #pragma unroll
        for (int j = 0; j < 8; ++j) acc[j] = bo[cb*8 + j];
        #pragma unroll
        for (int hc = 0; hc < 64; ++hc){
            const float gv = raw[hc];
            #pragma unroll
            for (int j = 0; j < 8; ++j)
                acc[j] = fmaf(gv, wo[hc*64 + cb*8 + j], acc[j]);
        }
        orow[cb*2+0] = make_float4(acc[0],acc[1],acc[2],acc[3]);
        orow[cb*2+1] = make_float4(acc[4],acc[5],acc[6],acc[7]);
    }
}

// ------------------------------------------------------------------------------------
extern "C" void kernel_launch(void* const* d_in, const int* in_sizes, int n_in,
                              void* d_out, int out_size, void* d_ws, size_t ws_size,
                              hipStream_t stream)
{
    const float* m    = (const float*)d_in[0];
    const float* mask = (const float*)d_in[1];
    const float* lnw  = (const float*)d_in[2];
    const float* lnb  = (const float*)d_in[3];
    const float* wq   = (const float*)d_in[4];
    const float* wk   = (const float*)d_in[5];
    const float* wv   = (const float*)d_in[6];
    const float* wg   = (const float*)d_in[7];
    const float* bg   = (const float*)d_in[8];
    const float* wo   = (const float*)d_in[9];
    const float* bo   = (const float*)d_in[10];
    float* ws  = (float*)d_ws;
    float* out = (float*)d_out;

    prep_mask<<<dim3((S_DIM * R_DIM) / 256), dim3(256), 0, stream>>>(mask, ws + OFF_MASKT);
    k1_kv_softmax<<<dim3(R_DIM), dim3(256), 0, stream>>>(
        m, lnw, lnb, wq, wk, wv, ws + OFF_MASKT,
        ws + OFF_QRED, ws + OFF_MSUM, ws + OFF_QH, ws + OFF_O);
    // qred region is dead after k1 -> fill it with the fused-LN gate weights
    prep_w<<<dim3(1), dim3(64), 0, stream>>>(
        lnw, lnb, wg, bg, ws + OFF_WG2, ws + OFF_CG, ws + OFF_DG);
    k2_gate_out<<<dim3((S_DIM * R_DIM) / 256), dim3(256), 0, stream>>>(
        m, ws + OFF_WG2, ws + OFF_CG, ws + OFF_DG, wo, bo, ws + OFF_O, out);
}